// Round 1
// baseline (134.956 us; speedup 1.0000x reference)
//
#include <hip/hip_runtime.h>
#include <float.h>
#include <math.h>

#define Bn 8
#define Cn 256
#define Hn 160
#define Wn 160
#define HWn (Hn * Wn)          // 25600
#define NPIX (Bn * HWn)        // 204800
#define NTOT (Bn * Cn * HWn)   // 52428800

// ---------------- Kernel 1: per-pixel channel mean + max ----------------
// 800 blocks x 256 threads. Block owns 256 consecutive pixels of one plane
// (HW=25600 is divisible by 256, so no block straddles a batch boundary).
// Wave wv reduces channels [wv*64, wv*64+64); lane handles 4 pixels (float4).
__global__ __launch_bounds__(256) void k_reduce(const float* __restrict__ x,
                                                float* __restrict__ avgp,
                                                float* __restrict__ maxp) {
    const int tid  = threadIdx.x;
    const int lane = tid & 63;
    const int wv   = tid >> 6;
    const int base = blockIdx.x << 8;            // first pixel of this block
    const int b    = base / HWn;
    const int hwb  = base - b * HWn;
    const float* xp = x + (size_t)b * Cn * HWn + hwb + (lane << 2);
    const int c0 = wv << 6;

    float4 s = make_float4(0.f, 0.f, 0.f, 0.f);
    float4 m = make_float4(-FLT_MAX, -FLT_MAX, -FLT_MAX, -FLT_MAX);
    #pragma unroll 8
    for (int c = 0; c < 64; ++c) {
        const float4 v = *reinterpret_cast<const float4*>(xp + (size_t)(c0 + c) * HWn);
        s.x += v.x; s.y += v.y; s.z += v.z; s.w += v.w;
        m.x = fmaxf(m.x, v.x); m.y = fmaxf(m.y, v.y);
        m.z = fmaxf(m.z, v.z); m.w = fmaxf(m.w, v.w);
    }

    __shared__ float4 ss[4][64];
    __shared__ float4 sm[4][64];
    ss[wv][lane] = s;
    sm[wv][lane] = m;
    __syncthreads();

    if (tid < 64) {
        const float4 s0 = ss[0][tid], s1 = ss[1][tid], s2 = ss[2][tid], s3 = ss[3][tid];
        const float4 m0 = sm[0][tid], m1 = sm[1][tid], m2 = sm[2][tid], m3 = sm[3][tid];
        const float inv = 1.0f / (float)Cn;
        float4 av, mx;
        av.x = (s0.x + s1.x + s2.x + s3.x) * inv;
        av.y = (s0.y + s1.y + s2.y + s3.y) * inv;
        av.z = (s0.z + s1.z + s2.z + s3.z) * inv;
        av.w = (s0.w + s1.w + s2.w + s3.w) * inv;
        mx.x = fmaxf(fmaxf(m0.x, m1.x), fmaxf(m2.x, m3.x));
        mx.y = fmaxf(fmaxf(m0.y, m1.y), fmaxf(m2.y, m3.y));
        mx.z = fmaxf(fmaxf(m0.z, m1.z), fmaxf(m2.z, m3.z));
        mx.w = fmaxf(fmaxf(m0.w, m1.w), fmaxf(m2.w, m3.w));
        reinterpret_cast<float4*>(avgp)[(base >> 2) + tid] = av;
        reinterpret_cast<float4*>(maxp)[(base >> 2) + tid] = mx;
    }
}

// ---------------- Kernel 2: 7x7 + 3x3 conv on [avg, max], sigmoid --------
// One thread per output pixel; desc planes are 1.6 MB total -> L2 resident.
// Zero padding == skip out-of-bounds taps. lax.conv is cross-correlation.
__global__ __launch_bounds__(256) void k_conv(const float* __restrict__ avgp,
                                              const float* __restrict__ maxp,
                                              const float* __restrict__ w7,
                                              const float* __restrict__ w3,
                                              const float* __restrict__ alphap,
                                              float* __restrict__ wmap) {
    const int p  = blockIdx.x * 256 + threadIdx.x;   // 0..NPIX-1
    const int b  = p / HWn;
    const int hw = p - b * HWn;
    const int h  = hw / Wn;
    const int w  = hw - h * Wn;
    const float* ap = avgp + b * HWn;
    const float* mp = maxp + b * HWn;

    float a7 = 0.f;
    #pragma unroll
    for (int kh = 0; kh < 7; ++kh) {
        const int hh = h + kh - 3;
        if (hh < 0 || hh >= Hn) continue;
        #pragma unroll
        for (int kw = 0; kw < 7; ++kw) {
            const int ww = w + kw - 3;
            if (ww < 0 || ww >= Wn) continue;
            const int o = hh * Wn + ww;
            a7 = fmaf(ap[o], w7[kh * 7 + kw], a7);
            a7 = fmaf(mp[o], w7[49 + kh * 7 + kw], a7);
        }
    }

    float a3 = 0.f;
    #pragma unroll
    for (int kh = 0; kh < 3; ++kh) {
        const int hh = h + kh - 1;
        if (hh < 0 || hh >= Hn) continue;
        #pragma unroll
        for (int kw = 0; kw < 3; ++kw) {
            const int ww = w + kw - 1;
            if (ww < 0 || ww >= Wn) continue;
            const int o = hh * Wn + ww;
            a3 = fmaf(ap[o], w3[kh * 3 + kw], a3);
            a3 = fmaf(mp[o], w3[9 + kh * 3 + kw], a3);
        }
    }

    const float alpha = *alphap;
    const float z = alpha * a7 + (1.0f - alpha) * a3;
    wmap[p] = 1.0f / (1.0f + expf(-z));
}

// ---------------- Kernel 3: out = x * w[b, hw] (broadcast over C) --------
__global__ __launch_bounds__(256) void k_mul(const float* __restrict__ x,
                                             const float* __restrict__ wmap,
                                             float* __restrict__ out) {
    const int n4   = NTOT / 4;
    const int chw4 = (Cn * HWn) / 4;   // 1638400
    const int hw4  = HWn / 4;          // 6400
    const int stride = gridDim.x * blockDim.x;
    for (int i = blockIdx.x * blockDim.x + threadIdx.x; i < n4; i += stride) {
        const int b  = i / chw4;
        const int r  = i - b * chw4;
        const int hw = r % hw4;        // float4 index within the HxW plane
        const float4 xv = reinterpret_cast<const float4*>(x)[i];
        const float4 wv = reinterpret_cast<const float4*>(wmap)[b * hw4 + hw];
        float4 o;
        o.x = xv.x * wv.x;
        o.y = xv.y * wv.y;
        o.z = xv.z * wv.z;
        o.w = xv.w * wv.w;
        reinterpret_cast<float4*>(out)[i] = o;
    }
}

extern "C" void kernel_launch(void* const* d_in, const int* in_sizes, int n_in,
                              void* d_out, int out_size, void* d_ws, size_t ws_size,
                              hipStream_t stream) {
    const float* x      = (const float*)d_in[0];
    const float* w7     = (const float*)d_in[1];
    const float* w3     = (const float*)d_in[2];
    const float* alphap = (const float*)d_in[3];
    float* out = (float*)d_out;

    float* avgp = (float*)d_ws;          // NPIX floats
    float* maxp = avgp + NPIX;           // NPIX floats
    float* wmap = maxp + NPIX;           // NPIX floats  (total 2.4 MB)

    k_reduce<<<NPIX / 256, 256, 0, stream>>>(x, avgp, maxp);
    k_conv<<<NPIX / 256, 256, 0, stream>>>(avgp, maxp, w7, w3, alphap, wmap);
    k_mul<<<2048, 256, 0, stream>>>(x, wmap, out);
}

// Round 3
// 112.011 us; speedup vs baseline: 1.2048x; 1.2048x over previous
//
#include <hip/hip_runtime.h>
#include <float.h>
#include <math.h>

#define Bn 8
#define Cn 256
#define Hn 160
#define Wn 160
#define HWn (Hn * Wn)          // 25600
#define NPIX (Bn * HWn)        // 204800
#define NTOT (Bn * Cn * HWn)   // 52428800

typedef float v4f __attribute__((ext_vector_type(4)));

// ---------------- Kernel 1: per-pixel channel mean + max ----------------
// 800 blocks x 256 threads. Block owns 256 consecutive pixels of one plane.
// Wave wv reduces channels [wv*64, wv*64+64); lane handles 4 pixels (float4).
__global__ __launch_bounds__(256) void k_reduce(const float* __restrict__ x,
                                                float* __restrict__ avgp,
                                                float* __restrict__ maxp) {
    const int tid  = threadIdx.x;
    const int lane = tid & 63;
    const int wv   = tid >> 6;
    const int base = blockIdx.x << 8;            // first pixel of this block
    const int b    = base / HWn;
    const int hwb  = base - b * HWn;
    const float* xp = x + (size_t)b * Cn * HWn + hwb + (lane << 2);
    const int c0 = wv << 6;

    float4 s = make_float4(0.f, 0.f, 0.f, 0.f);
    float4 m = make_float4(-FLT_MAX, -FLT_MAX, -FLT_MAX, -FLT_MAX);
    #pragma unroll 8
    for (int c = 0; c < 64; ++c) {
        const float4 v = *reinterpret_cast<const float4*>(xp + (size_t)(c0 + c) * HWn);
        s.x += v.x; s.y += v.y; s.z += v.z; s.w += v.w;
        m.x = fmaxf(m.x, v.x); m.y = fmaxf(m.y, v.y);
        m.z = fmaxf(m.z, v.z); m.w = fmaxf(m.w, v.w);
    }

    __shared__ float4 ss[4][64];
    __shared__ float4 sm[4][64];
    ss[wv][lane] = s;
    sm[wv][lane] = m;
    __syncthreads();

    if (tid < 64) {
        const float4 s0 = ss[0][tid], s1 = ss[1][tid], s2 = ss[2][tid], s3 = ss[3][tid];
        const float4 m0 = sm[0][tid], m1 = sm[1][tid], m2 = sm[2][tid], m3 = sm[3][tid];
        const float inv = 1.0f / (float)Cn;
        float4 av, mx;
        av.x = (s0.x + s1.x + s2.x + s3.x) * inv;
        av.y = (s0.y + s1.y + s2.y + s3.y) * inv;
        av.z = (s0.z + s1.z + s2.z + s3.z) * inv;
        av.w = (s0.w + s1.w + s2.w + s3.w) * inv;
        mx.x = fmaxf(fmaxf(m0.x, m1.x), fmaxf(m2.x, m3.x));
        mx.y = fmaxf(fmaxf(m0.y, m1.y), fmaxf(m2.y, m3.y));
        mx.z = fmaxf(fmaxf(m0.z, m1.z), fmaxf(m2.z, m3.z));
        mx.w = fmaxf(fmaxf(m0.w, m1.w), fmaxf(m2.w, m3.w));
        reinterpret_cast<float4*>(avgp)[(base >> 2) + tid] = av;
        reinterpret_cast<float4*>(maxp)[(base >> 2) + tid] = mx;
    }
}

// ---------------- Kernel 2: 7x7 + 3x3 conv on [avg, max], sigmoid --------
// One thread per output pixel; desc planes are 1.6 MB total -> L2/L3 resident.
// Zero padding == skip out-of-bounds taps. lax.conv is cross-correlation.
__global__ __launch_bounds__(256) void k_conv(const float* __restrict__ avgp,
                                              const float* __restrict__ maxp,
                                              const float* __restrict__ w7,
                                              const float* __restrict__ w3,
                                              const float* __restrict__ alphap,
                                              float* __restrict__ wmap) {
    const int p  = blockIdx.x * 256 + threadIdx.x;   // 0..NPIX-1
    const int b  = p / HWn;
    const int hw = p - b * HWn;
    const int h  = hw / Wn;
    const int w  = hw - h * Wn;
    const float* ap = avgp + b * HWn;
    const float* mp = maxp + b * HWn;

    float a7 = 0.f;
    #pragma unroll
    for (int kh = 0; kh < 7; ++kh) {
        const int hh = h + kh - 3;
        if (hh < 0 || hh >= Hn) continue;
        #pragma unroll
        for (int kw = 0; kw < 7; ++kw) {
            const int ww = w + kw - 3;
            if (ww < 0 || ww >= Wn) continue;
            const int o = hh * Wn + ww;
            a7 = fmaf(ap[o], w7[kh * 7 + kw], a7);
            a7 = fmaf(mp[o], w7[49 + kh * 7 + kw], a7);
        }
    }

    float a3 = 0.f;
    #pragma unroll
    for (int kh = 0; kh < 3; ++kh) {
        const int hh = h + kh - 1;
        if (hh < 0 || hh >= Hn) continue;
        #pragma unroll
        for (int kw = 0; kw < 3; ++kw) {
            const int ww = w + kw - 1;
            if (ww < 0 || ww >= Wn) continue;
            const int o = hh * Wn + ww;
            a3 = fmaf(ap[o], w3[kh * 3 + kw], a3);
            a3 = fmaf(mp[o], w3[9 + kh * 3 + kw], a3);
        }
    }

    const float alpha = *alphap;
    const float z = alpha * a7 + (1.0f - alpha) * a3;
    wmap[p] = 1.0f / (1.0f + expf(-z));
}

// ---------------- Kernel 3: out = x * w[b, hw] (broadcast over C) --------
// Non-temporal stores: out is never re-read -> don't let the 210 MB of
// stores evict x (210 MB, L3-resident) from the 256 MB Infinity Cache.
__global__ __launch_bounds__(256) void k_mul(const float* __restrict__ x,
                                             const float* __restrict__ wmap,
                                             float* __restrict__ out) {
    const int n4   = NTOT / 4;
    const int chw4 = (Cn * HWn) / 4;   // 1638400
    const int hw4  = HWn / 4;          // 6400
    const int stride = gridDim.x * blockDim.x;
    for (int i = blockIdx.x * blockDim.x + threadIdx.x; i < n4; i += stride) {
        const int b  = i / chw4;
        const int r  = i - b * chw4;
        const int hw = r % hw4;        // float4 index within the HxW plane
        const v4f xv = *(reinterpret_cast<const v4f*>(x) + i);
        const float4 wv = reinterpret_cast<const float4*>(wmap)[b * hw4 + hw];
        v4f o;
        o.x = xv.x * wv.x;
        o.y = xv.y * wv.y;
        o.z = xv.z * wv.z;
        o.w = xv.w * wv.w;
        __builtin_nontemporal_store(o, reinterpret_cast<v4f*>(out) + i);
    }
}

extern "C" void kernel_launch(void* const* d_in, const int* in_sizes, int n_in,
                              void* d_out, int out_size, void* d_ws, size_t ws_size,
                              hipStream_t stream) {
    const float* x      = (const float*)d_in[0];
    const float* w7     = (const float*)d_in[1];
    const float* w3     = (const float*)d_in[2];
    const float* alphap = (const float*)d_in[3];
    float* out = (float*)d_out;

    float* avgp = (float*)d_ws;          // NPIX floats
    float* maxp = avgp + NPIX;           // NPIX floats
    float* wmap = maxp + NPIX;           // NPIX floats  (total 2.4 MB)

    k_reduce<<<NPIX / 256, 256, 0, stream>>>(x, avgp, maxp);
    k_conv<<<NPIX / 256, 256, 0, stream>>>(avgp, maxp, w7, w3, alphap, wmap);
    k_mul<<<4096, 256, 0, stream>>>(x, wmap, out);
}